// Round 8
// baseline (162.187 us; speedup 1.0000x reference)
//
#include <hip/hip_runtime.h>

#define IMG 512
#define CS 36                     // shorts per Ht column: 2 ring slots (32) + 4 pad
#define CH_STRIDE (16 * CS)       // 576 shorts: one channel (16 cols)
#define WV_STRIDE (5 * CH_STRIDE) // 2880 shorts: 5 channels (one strip)

typedef short short8  __attribute__((ext_vector_type(8)));
typedef float floatx4 __attribute__((ext_vector_type(4)));
typedef int   intx2   __attribute__((ext_vector_type(2)));

// 1D Gaussian (sigma=1.5, K=11) — identical values to prior rounds.
__device__ static constexpr float W11F[11] = {
    0.00102838f, 0.00759876f, 0.03600077f, 0.10936069f, 0.21300554f,
    0.26601173f,
    0.21300554f, 0.10936069f, 0.03600077f, 0.00759876f, 0.00102838f};

__device__ __forceinline__ unsigned pack2bf16(float a, float b) {
    const unsigned ua = __float_as_uint(a) + 0x8000u;
    const unsigned ub = __float_as_uint(b) + 0x8000u;
    return __builtin_amdgcn_perm(ub, ua, 0x07060302u);
}

__device__ __forceinline__ void ht_store(ushort* p, floatx4 c) {
    intx2 d;
    d.x = (int)pack2bf16(c[0], c[1]);
    d.y = (int)pack2bf16(c[2], c[3]);
    *(intx2*)p = d;               // 8-B aligned by construction
}

__device__ __forceinline__ short8 ht_load(const ushort* p) {
    union { intx2 d[2]; short8 s; } u;
    u.d[0] = *(const intx2*)p;
    u.d[1] = *(const intx2*)(p + 4);
    return u.s;
}

// DUAL-STRIP ILP kernel. Block = 4 waves (256 thr); each wave owns TWO
// independent 16-col x 128-row output strips (64 cols apart) and runs
// both dependency chains interleaved in one instruction stream. Rationale
// (rounds 0-7): duration ~70-76us is invariant to occupancy (10-39%),
// prefetch depth, staging style (scattered reg / coalesced LDS-DMA), and
// data source (L3-resident == HBM) -> latency-bound on the per-wave
// serial chain (ds_read ~120cy, MFMA latency, H->ring->V round trip),
// with VALUBusy pinned at ~26% regardless of wave count. Two chains per
// wave let chain-1 issue under chain-0's stalls (and vice versa),
// doubling per-wave issue density without touching the (irrelevant)
// memory system. Roll structure from round 4: 9 tiles / 8 windows per
// strip stream through a 2-slot ring; register staging; no inner barriers.
__global__ __launch_bounds__(256, 4) void ssim_mfma_dual(
        const float* __restrict__ pred, const float* __restrict__ gt,
        float* __restrict__ partials)
{
    __shared__ ushort Ht[8 * WV_STRIDE];   // 4 waves x 2 strips = 46,080 B
    __shared__ ushort wlut[16];
    __shared__ float wsum[4];

    const int tid  = threadIdx.x;
    const int wv   = tid >> 6;
    const int lane = tid & 63;
    const int n    = lane & 15;
    const int quad = lane >> 4;

    if (tid < 16) {
        const float w = (tid < 11) ? W11F[tid] : 0.f;
        wlut[tid] = (ushort)((__float_as_uint(w) + 0x8000u) >> 16);
    }
    __syncthreads();

    // band fragment: w[(quad*8+j) - n - 3]; B in H-pass, A in V-pass.
    short8 band;
#pragma unroll
    for (int j = 0; j < 8; ++j) {
        const int t = quad * 8 + j - n - 3;
        band[j] = (short)wlut[((unsigned)t < 11u) ? t : 15];
    }

    const int bx = blockIdx.x, yh = blockIdx.y, plane = blockIdx.z;
    const long pb = (long)plane * (IMG * IMG);
    const float* pplane = pred + pb;
    const float* gplane = gt + pb;
    const int y0  = yh * 128;               // 128-row output strip
    // strip 0: cols bx*128 + wv*16; strip 1: +64
    const int xs0 = bx * 128 + wv * 16 - 8;
    const int xs1 = xs0 + 64;
    ushort* ht0   = &Ht[(wv * 2 + 0) * WV_STRIDE];
    ushort* ht1   = &Ht[(wv * 2 + 1) * WV_STRIDE];
    const bool cok0 = (xs0 >= 0) && (xs0 + 32 <= IMG);
    const bool cok1 = (xs1 >= 0) && (xs1 + 32 <= IMG);

// stage tile t (16 input rows starting at y0-8+16t) into named buffers
#define LOADT(t, pf, gf, XS, COK)                                            \
    {                                                                        \
        const int ys  = y0 - 8 + (t) * 16;                                   \
        const int row = ys + n;                                              \
        const int c0  = (XS) + quad * 8;                                     \
        if ((COK) && ys >= 0 && ys + 16 <= IMG) {                            \
            const float* pr = pplane + (long)row * IMG + c0;                 \
            const float* gr = gplane + (long)row * IMG + c0;                 \
            *(float4*)&pf[0] = *(const float4*)pr;                           \
            *(float4*)&pf[4] = *(const float4*)(pr + 4);                     \
            *(float4*)&gf[0] = *(const float4*)gr;                           \
            *(float4*)&gf[4] = *(const float4*)(gr + 4);                     \
        } else {                                                             \
            const bool rv = (unsigned)row < (unsigned)IMG;                   \
            const int rowc = rv ? row : 0;                                   \
            const float* pr = pplane + (long)rowc * IMG;                     \
            const float* gr = gplane + (long)rowc * IMG;                     \
            _Pragma("unroll")                                                \
            for (int j = 0; j < 8; ++j) {                                    \
                const int cc = c0 + j;                                       \
                const bool ok = rv && ((unsigned)cc < (unsigned)IMG);        \
                const int ccc = ok ? cc : 0;                                 \
                const float pv = pr[ccc], gv = gr[ccc];                      \
                pf[j] = ok ? pv : 0.f;                                       \
                gf[j] = ok ? gv : 0.f;                                       \
            }                                                                \
        }                                                                    \
    }

// H-conv tile t via 5 MFMAs, store into ring slot t&1 of HT
#define COMPT(t, pf, gf, HT)                                                 \
    {                                                                        \
        union { unsigned u[4]; short8 s; } ap, ag, app, agg, apg;            \
        _Pragma("unroll")                                                    \
        for (int h = 0; h < 4; ++h) {                                        \
            const float p0 = pf[2*h], p1 = pf[2*h+1];                        \
            const float g0 = gf[2*h], g1 = gf[2*h+1];                        \
            ap.u [h] = pack2bf16(p0, p1);                                    \
            ag.u [h] = pack2bf16(g0, g1);                                    \
            app.u[h] = pack2bf16(p0 * p0, p1 * p1);                          \
            agg.u[h] = pack2bf16(g0 * g0, g1 * g1);                          \
            apg.u[h] = pack2bf16(p0 * g0, p1 * g1);                          \
        }                                                                    \
        const floatx4 z = {0.f, 0.f, 0.f, 0.f};                              \
        const floatx4 cp  = __builtin_amdgcn_mfma_f32_16x16x32_bf16(ap.s,  band, z, 0, 0, 0); \
        const floatx4 cg  = __builtin_amdgcn_mfma_f32_16x16x32_bf16(ag.s,  band, z, 0, 0, 0); \
        const floatx4 cpp = __builtin_amdgcn_mfma_f32_16x16x32_bf16(app.s, band, z, 0, 0, 0); \
        const floatx4 cgg = __builtin_amdgcn_mfma_f32_16x16x32_bf16(agg.s, band, z, 0, 0, 0); \
        const floatx4 cpg = __builtin_amdgcn_mfma_f32_16x16x32_bf16(apg.s, band, z, 0, 0, 0); \
        const int wb = n * CS + ((t) & 1) * 16 + quad * 4;                   \
        ht_store(&(HT)[0 * CH_STRIDE + wb], cp);                             \
        ht_store(&(HT)[1 * CH_STRIDE + wb], cg);                             \
        ht_store(&(HT)[2 * CH_STRIDE + wb], cpp);                            \
        ht_store(&(HT)[3 * CH_STRIDE + wb], cgg);                            \
        ht_store(&(HT)[4 * CH_STRIDE + wb], cpg);                            \
    }

// V window: lower 16 k-rows from ring slot SLO, upper from slot SHI of HT
#define VPASS(SLO, SHI, HT)                                                  \
    {                                                                        \
        const int koff = ((quad < 2) ? (SLO) : (SHI)) * 16 + (quad & 1) * 8; \
        const int rb   = n * CS + koff;                                      \
        const short8 bp  = ht_load(&(HT)[0 * CH_STRIDE + rb]);               \
        const short8 bg  = ht_load(&(HT)[1 * CH_STRIDE + rb]);               \
        const short8 bpp = ht_load(&(HT)[2 * CH_STRIDE + rb]);               \
        const short8 bgg = ht_load(&(HT)[3 * CH_STRIDE + rb]);               \
        const short8 bpg = ht_load(&(HT)[4 * CH_STRIDE + rb]);               \
        const floatx4 z = {0.f, 0.f, 0.f, 0.f};                              \
        const floatx4 mp  = __builtin_amdgcn_mfma_f32_16x16x32_bf16(band, bp,  z, 0, 0, 0); \
        const floatx4 mg  = __builtin_amdgcn_mfma_f32_16x16x32_bf16(band, bg,  z, 0, 0, 0); \
        const floatx4 mpp = __builtin_amdgcn_mfma_f32_16x16x32_bf16(band, bpp, z, 0, 0, 0); \
        const floatx4 mgg = __builtin_amdgcn_mfma_f32_16x16x32_bf16(band, bgg, z, 0, 0, 0); \
        const floatx4 mpg = __builtin_amdgcn_mfma_f32_16x16x32_bf16(band, bpg, z, 0, 0, 0); \
        _Pragma("unroll")                                                    \
        for (int r = 0; r < 4; ++r) {                                        \
            const float mu1 = mp[r], mu2 = mg[r];                            \
            const float mu1sq = mu1 * mu1, mu2sq = mu2 * mu2;                \
            const float mu12 = mu1 * mu2;                                    \
            const float s1  = mpp[r] - mu1sq;                                \
            const float s2  = mgg[r] - mu2sq;                                \
            const float s12 = mpg[r] - mu12;                                 \
            const float num = (2.f * mu12 + C1) * (2.f * s12 + C2);          \
            const float den = (mu1sq + mu2sq + C1) * (s1 + s2 + C2);         \
            lsum += num * __builtin_amdgcn_rcpf(den);                        \
        }                                                                    \
    }

    const float C1 = 1e-4f, C2 = 9e-4f;
    float lsum = 0.f;

    // 2 register buffer sets PER STRIP, rolled: buffer parity == tile parity
    float pA0[8], gA0[8], pB0[8], gB0[8];
    float pA1[8], gA1[8], pB1[8], gB1[8];

    // ---- pipeline fill (both strips interleaved) ----
    LOADT(0, pA0, gA0, xs0, cok0) LOADT(0, pA1, gA1, xs1, cok1)
    LOADT(1, pB0, gB0, xs0, cok0) LOADT(1, pB1, gB1, xs1, cok1)
    COMPT(0, pA0, gA0, ht0)       COMPT(0, pA1, gA1, ht1)       // slot 0
    LOADT(2, pA0, gA0, xs0, cok0) LOADT(2, pA1, gA1, xs1, cok1)
    COMPT(1, pB0, gB0, ht0)       COMPT(1, pB1, gB1, ht1)       // slot 1
    VPASS(0, 1, ht0)              VPASS(0, 1, ht1)              // window 0

    // ---- steady state: 2 tiles / 2 windows per iteration, per strip ----
    for (int t = 2; t <= 6; t += 2) {
        LOADT(t + 1, pB0, gB0, xs0, cok0) LOADT(t + 1, pB1, gB1, xs1, cok1)
        COMPT(t, pA0, gA0, ht0)           COMPT(t, pA1, gA1, ht1)   // slot 0
        VPASS(1, 0, ht0)                  VPASS(1, 0, ht1)          // window t-1
        LOADT(t + 2, pA0, gA0, xs0, cok0) LOADT(t + 2, pA1, gA1, xs1, cok1)
        COMPT(t + 1, pB0, gB0, ht0)       COMPT(t + 1, pB1, gB1, ht1) // slot 1
        VPASS(0, 1, ht0)                  VPASS(0, 1, ht1)          // window t
    }

    // ---- drain: tiles 0..8 loaded, 0..7 computed, windows 0..6 done ----
    COMPT(8, pA0, gA0, ht0) COMPT(8, pA1, gA1, ht1)                 // slot 0
    VPASS(1, 0, ht0)        VPASS(1, 0, ht1)                        // window 7

    // ---- block reduction -> one partial per block ----
#pragma unroll
    for (int off = 32; off > 0; off >>= 1)
        lsum += __shfl_down(lsum, off);
    if (lane == 0) wsum[wv] = lsum;
    __syncthreads();
    if (tid == 0)
        partials[(plane * 4 + yh) * 4 + bx] =
            wsum[0] + wsum[1] + wsum[2] + wsum[3];
}

__global__ __launch_bounds__(1024) void ssim_finalize(
        const float* __restrict__ partials, float* __restrict__ out,
        int nparts, double inv_n)
{
    __shared__ double ws[16];
    double s = 0.0;
    for (int i = threadIdx.x; i < nparts; i += 1024)
        s += (double)partials[i];
#pragma unroll
    for (int off = 32; off > 0; off >>= 1)
        s += __shfl_down(s, off);
    if ((threadIdx.x & 63) == 0) ws[threadIdx.x >> 6] = s;
    __syncthreads();
    if (threadIdx.x == 0) {
        double t = 0.0;
#pragma unroll
        for (int i = 0; i < 16; ++i) t += ws[i];
        out[0] = (float)(1.0 - t * inv_n);
    }
}

extern "C" void kernel_launch(void* const* d_in, const int* in_sizes, int n_in,
                              void* d_out, int out_size, void* d_ws, size_t ws_size,
                              hipStream_t stream)
{
    const float* pred = (const float*)d_in[0];
    const float* gt   = (const float*)d_in[1];
    float* out        = (float*)d_out;
    float* partials   = (float*)d_ws;          // 4*4*48 = 768 floats

    const long n = (long)in_sizes[0];
    const int planes = (int)(n / (long)(IMG * IMG));   // B*C = 48

    dim3 grid(4, 4, planes);                   // 128-col x 128-row blocks
    ssim_mfma_dual<<<grid, 256, 0, stream>>>(pred, gt, partials);
    ssim_finalize<<<1, 1024, 0, stream>>>(partials, out,
                                          4 * 4 * planes, 1.0 / (double)n);
}

// Round 9
// 154.678 us; speedup vs baseline: 1.0485x; 1.0485x over previous
//
#include <hip/hip_runtime.h>

#define IMG 512

typedef short short8  __attribute__((ext_vector_type(8)));
typedef float floatx4 __attribute__((ext_vector_type(4)));
typedef unsigned uvec2 __attribute__((ext_vector_type(2)));

// 1D Gaussian (sigma=1.5, K=11) — identical values to prior rounds.
__device__ static constexpr float W11F[11] = {
    0.00102838f, 0.00759876f, 0.03600077f, 0.10936069f, 0.21300554f,
    0.26601173f,
    0.21300554f, 0.10936069f, 0.03600077f, 0.00759876f, 0.00102838f};

// pack two fp32 -> one u32 of two bf16 (lo=a, hi=b semantics as verified
// by rounds 0-8: consecutive (even,odd) rows pack as (lo,hi))
__device__ __forceinline__ unsigned pack2bf16(float a, float b) {
    const unsigned ua = __float_as_uint(a) + 0x8000u;
    const unsigned ub = __float_as_uint(b) + 0x8000u;
    return __builtin_amdgcn_perm(ub, ua, 0x07060302u);
}

// LDS-FREE kernel. Rounds 0-8 established: duration ~70-76us invariant to
// occupancy (10-39%), prefetch depth, staging style, data source
// (L3-resident == HBM), block lifetime, and intra-wave dual-chain ILP;
// VALUBusy pinned ~26%. The one untouched structural element was the
// H->LDS->V transpose (5 ds_write + 10 ds_read + in-order lgkm waits per
// window, ~120cy each). This version eliminates LDS from the loop: the
// H-pass D layout (col=lane&15, row=quad*4+reg) and V-pass B-fragment
// layout (col=lane&15, k=quad*8+j) share the column->lane mapping, so the
// inter-pass redistribution is exactly 2x permlane32_swap + 2x
// permlane16_swap per quantity (pure VALU cross-lane):
//   (A1,B1) = pl32swap(LO.pk, HI.pk)   // [L0,L1,H0,H1],[L2,L3,H2,H3]
//   (b0,b2) = pl16swap(A1, B1)         // [L0,L2,H0,H2],[L1,L3,H1,H3]
// Roll structure from round 4 (best, 70.5us): wave = 16 cols x 256 rows,
// 17 tiles / 16 windows, 2 register buffer sets, no barriers in loop.
__global__ __launch_bounds__(256) void ssim_mfma_reg(
        const float* __restrict__ pred, const float* __restrict__ gt,
        float* __restrict__ partials)
{
    __shared__ ushort wlut[16];
    __shared__ float wsum[4];

    const int tid  = threadIdx.x;
    const int wv   = tid >> 6;
    const int lane = tid & 63;
    const int n    = lane & 15;
    const int quad = lane >> 4;

    if (tid < 16) {
        const float w = (tid < 11) ? W11F[tid] : 0.f;
        wlut[tid] = (ushort)((__float_as_uint(w) + 0x8000u) >> 16);
    }
    __syncthreads();

    // band fragment: w[(quad*8+j) - n - 3]; B in H-pass, A in V-pass.
    short8 band;
#pragma unroll
    for (int j = 0; j < 8; ++j) {
        const int t = quad * 8 + j - n - 3;
        band[j] = (short)wlut[((unsigned)t < 11u) ? t : 15];
    }

    const int bx = blockIdx.x, yh = blockIdx.y, plane = blockIdx.z;
    const long pb = (long)plane * (IMG * IMG);
    const float* pplane = pred + pb;
    const float* gplane = gt + pb;
    const int xs  = bx * 64 + wv * 16 - 8;  // 32-col input window start
    const int y0  = yh * 256;               // 256-row output strip
    const bool cols_ok = (xs >= 0) && (xs + 32 <= IMG);

// stage tile t (16 input rows starting at y0-8+16t) into named buffers
#define LOADT(t, pf, gf)                                                     \
    {                                                                        \
        const int ys  = y0 - 8 + (t) * 16;                                   \
        const int row = ys + n;                                              \
        const int c0  = xs + quad * 8;                                       \
        if (cols_ok && ys >= 0 && ys + 16 <= IMG) {                          \
            const float* pr = pplane + (long)row * IMG + c0;                 \
            const float* gr = gplane + (long)row * IMG + c0;                 \
            *(float4*)&pf[0] = *(const float4*)pr;                           \
            *(float4*)&pf[4] = *(const float4*)(pr + 4);                     \
            *(float4*)&gf[0] = *(const float4*)gr;                           \
            *(float4*)&gf[4] = *(const float4*)(gr + 4);                     \
        } else {                                                             \
            const bool rv = (unsigned)row < (unsigned)IMG;                   \
            const int rowc = rv ? row : 0;                                   \
            const float* pr = pplane + (long)rowc * IMG;                     \
            const float* gr = gplane + (long)rowc * IMG;                     \
            _Pragma("unroll")                                                \
            for (int j = 0; j < 8; ++j) {                                    \
                const int cc = c0 + j;                                       \
                const bool ok = rv && ((unsigned)cc < (unsigned)IMG);        \
                const int ccc = ok ? cc : 0;                                 \
                const float pv = pr[ccc], gv = gr[ccc];                      \
                pf[j] = ok ? pv : 0.f;                                       \
                gf[j] = ok ? gv : 0.f;                                       \
            }                                                                \
        }                                                                    \
    }

// H-conv tile via 5 MFMAs; pack D into PK[10] (2 u32 per quantity):
// PK[2q+i] covers rows (4*quad + 2i, +1) of quantity q at out-col n.
#define COMPH(pf, gf, PK)                                                    \
    {                                                                        \
        union { unsigned u[4]; short8 s; } ap, ag, app, agg, apg;            \
        _Pragma("unroll")                                                    \
        for (int h = 0; h < 4; ++h) {                                        \
            const float p0 = pf[2*h], p1 = pf[2*h+1];                        \
            const float g0 = gf[2*h], g1 = gf[2*h+1];                        \
            ap.u [h] = pack2bf16(p0, p1);                                    \
            ag.u [h] = pack2bf16(g0, g1);                                    \
            app.u[h] = pack2bf16(p0 * p0, p1 * p1);                          \
            agg.u[h] = pack2bf16(g0 * g0, g1 * g1);                          \
            apg.u[h] = pack2bf16(p0 * g0, p1 * g1);                          \
        }                                                                    \
        const floatx4 z = {0.f, 0.f, 0.f, 0.f};                              \
        const floatx4 cp  = __builtin_amdgcn_mfma_f32_16x16x32_bf16(ap.s,  band, z, 0, 0, 0); \
        const floatx4 cg  = __builtin_amdgcn_mfma_f32_16x16x32_bf16(ag.s,  band, z, 0, 0, 0); \
        const floatx4 cpp = __builtin_amdgcn_mfma_f32_16x16x32_bf16(app.s, band, z, 0, 0, 0); \
        const floatx4 cgg = __builtin_amdgcn_mfma_f32_16x16x32_bf16(agg.s, band, z, 0, 0, 0); \
        const floatx4 cpg = __builtin_amdgcn_mfma_f32_16x16x32_bf16(apg.s, band, z, 0, 0, 0); \
        PK[0] = pack2bf16(cp [0], cp [1]); PK[1] = pack2bf16(cp [2], cp [3]); \
        PK[2] = pack2bf16(cg [0], cg [1]); PK[3] = pack2bf16(cg [2], cg [3]); \
        PK[4] = pack2bf16(cpp[0], cpp[1]); PK[5] = pack2bf16(cpp[2], cpp[3]); \
        PK[6] = pack2bf16(cgg[0], cgg[1]); PK[7] = pack2bf16(cgg[2], cgg[3]); \
        PK[8] = pack2bf16(cpg[0], cpg[1]); PK[9] = pack2bf16(cpg[2], cpg[3]); \
    }

// build V-pass B-fragment for quantity q from packed LO/HI tiles:
// dest quad q' element j = H-row (8q'&15 + j) of tile (q'<2 ? LO : HI)
#define BFRAG(PLO, PHI, q, OUT)                                              \
    short8 OUT;                                                              \
    {                                                                        \
        const uvec2 s0 = __builtin_amdgcn_permlane32_swap(                   \
            PLO[2*(q)],     PHI[2*(q)],     false, false);                   \
        const uvec2 t0 = __builtin_amdgcn_permlane16_swap(                   \
            s0[0], s0[1], false, false);                                     \
        const uvec2 s1 = __builtin_amdgcn_permlane32_swap(                   \
            PLO[2*(q)+1],   PHI[2*(q)+1],   false, false);                   \
        const uvec2 t1 = __builtin_amdgcn_permlane16_swap(                   \
            s1[0], s1[1], false, false);                                     \
        union { unsigned u[4]; short8 s; } b_;                               \
        b_.u[0] = t0[0]; b_.u[1] = t1[0]; b_.u[2] = t0[1]; b_.u[3] = t1[1];  \
        OUT = b_.s;                                                          \
    }

// V window: LO = packed tile w, HI = packed tile w+1 (in-register)
#define VWIN(PLO, PHI)                                                       \
    {                                                                        \
        BFRAG(PLO, PHI, 0, bp)                                               \
        BFRAG(PLO, PHI, 1, bg)                                               \
        BFRAG(PLO, PHI, 2, bpp)                                              \
        BFRAG(PLO, PHI, 3, bgg)                                              \
        BFRAG(PLO, PHI, 4, bpg)                                              \
        const floatx4 z = {0.f, 0.f, 0.f, 0.f};                              \
        const floatx4 mp  = __builtin_amdgcn_mfma_f32_16x16x32_bf16(band, bp,  z, 0, 0, 0); \
        const floatx4 mg  = __builtin_amdgcn_mfma_f32_16x16x32_bf16(band, bg,  z, 0, 0, 0); \
        const floatx4 mpp = __builtin_amdgcn_mfma_f32_16x16x32_bf16(band, bpp, z, 0, 0, 0); \
        const floatx4 mgg = __builtin_amdgcn_mfma_f32_16x16x32_bf16(band, bgg, z, 0, 0, 0); \
        const floatx4 mpg = __builtin_amdgcn_mfma_f32_16x16x32_bf16(band, bpg, z, 0, 0, 0); \
        _Pragma("unroll")                                                    \
        for (int r = 0; r < 4; ++r) {                                        \
            const float mu1 = mp[r], mu2 = mg[r];                            \
            const float mu1sq = mu1 * mu1, mu2sq = mu2 * mu2;                \
            const float mu12 = mu1 * mu2;                                    \
            const float s1  = mpp[r] - mu1sq;                                \
            const float s2  = mgg[r] - mu2sq;                                \
            const float s12 = mpg[r] - mu12;                                 \
            const float num = (2.f * mu12 + C1) * (2.f * s12 + C2);          \
            const float den = (mu1sq + mu2sq + C1) * (s1 + s2 + C2);         \
            lsum += num * __builtin_amdgcn_rcpf(den);                        \
        }                                                                    \
    }

    const float C1 = 1e-4f, C2 = 9e-4f;
    float lsum = 0.f;

    // named register state only: 2 load buffer sets + 2 packed-tile sets
    float pA[8], gA[8], pB[8], gB[8];
    unsigned PKE[10], PKO[10];

    // ---- pipeline fill ----
    LOADT(0, pA, gA)
    LOADT(1, pB, gB)
    COMPH(pA, gA, PKE)        // tile 0
    LOADT(2, pA, gA)
    COMPH(pB, gB, PKO)        // tile 1
    VWIN(PKE, PKO)            // window 0: tiles 0,1

    // ---- steady state: 2 tiles / 2 windows per iteration ----
    for (int t = 2; t <= 14; t += 2) {
        LOADT(t + 1, pB, gB)
        COMPH(pA, gA, PKE)    // tile t
        VWIN(PKO, PKE)        // window t-1: tiles t-1,t
        LOADT(t + 2, pA, gA)
        COMPH(pB, gB, PKO)    // tile t+1
        VWIN(PKE, PKO)        // window t: tiles t,t+1
    }

    // ---- drain: tiles 0..16 loaded, windows 0..14 done ----
    COMPH(pA, gA, PKE)        // tile 16
    VWIN(PKO, PKE)            // window 15: tiles 15,16

    // ---- block reduction -> one partial per block ----
#pragma unroll
    for (int off = 32; off > 0; off >>= 1)
        lsum += __shfl_down(lsum, off);
    if (lane == 0) wsum[wv] = lsum;
    __syncthreads();
    if (tid == 0)
        partials[(plane * 2 + yh) * 8 + bx] =
            wsum[0] + wsum[1] + wsum[2] + wsum[3];
}

__global__ __launch_bounds__(1024) void ssim_finalize(
        const float* __restrict__ partials, float* __restrict__ out,
        int nparts, double inv_n)
{
    __shared__ double ws[16];
    double s = 0.0;
    for (int i = threadIdx.x; i < nparts; i += 1024)
        s += (double)partials[i];
#pragma unroll
    for (int off = 32; off > 0; off >>= 1)
        s += __shfl_down(s, off);
    if ((threadIdx.x & 63) == 0) ws[threadIdx.x >> 6] = s;
    __syncthreads();
    if (threadIdx.x == 0) {
        double t = 0.0;
#pragma unroll
        for (int i = 0; i < 16; ++i) t += ws[i];
        out[0] = (float)(1.0 - t * inv_n);
    }
}

extern "C" void kernel_launch(void* const* d_in, const int* in_sizes, int n_in,
                              void* d_out, int out_size, void* d_ws, size_t ws_size,
                              hipStream_t stream)
{
    const float* pred = (const float*)d_in[0];
    const float* gt   = (const float*)d_in[1];
    float* out        = (float*)d_out;
    float* partials   = (float*)d_ws;          // 8*2*48 = 768 floats

    const long n = (long)in_sizes[0];
    const int planes = (int)(n / (long)(IMG * IMG));   // B*C = 48

    dim3 grid(8, 2, planes);                   // 64-col x 256-row strips
    ssim_mfma_reg<<<grid, 256, 0, stream>>>(pred, gt, partials);
    ssim_finalize<<<1, 1024, 0, stream>>>(partials, out,
                                          8 * 2 * planes, 1.0 / (double)n);
}